// Round 13
// baseline (380.989 us; speedup 1.0000x reference)
//
#include <hip/hip_runtime.h>
#include <cstdint>

#define D_MODEL 1024
#define D_INNER 2048
#define LSEQ    4096
#define BATCH   2
#define M_ROWS  (BATCH * LSEQ)   // 8192
#define CHUNK   128
#define NCHUNK  (LSEQ / CHUNK)   // 32

typedef unsigned short u16;
typedef __bf16 bf16x8 __attribute__((ext_vector_type(8)));
typedef float f32x4 __attribute__((ext_vector_type(4)));
typedef u16 u16x4 __attribute__((ext_vector_type(4)));

__device__ __forceinline__ u16 f2bf(float f) {
  union { float f; unsigned u; } x; x.f = f;
  unsigned u = x.u;
  unsigned r = (u + 0x7FFFu + ((u >> 16) & 1u)) >> 16;
  return (u16)r;
}
__device__ __forceinline__ float bf2f(u16 h) {
  union { unsigned u; float f; } x; x.u = ((unsigned)h) << 16;
  return x.f;
}
__device__ __forceinline__ float sigmoidf_(float v) { return 1.0f / (1.0f + expf(-v)); }
__device__ __forceinline__ float siluf_(float v)    { return v / (1.0f + expf(-v)); }

__device__ __forceinline__ void gl_lds16(const void* g, void* l) {
  __builtin_amdgcn_global_load_lds(
      (const __attribute__((address_space(1))) void*)g,
      (__attribute__((address_space(3))) void*)l, 16, 0, 0);
}

#define SBAR()   asm volatile("s_barrier" ::: "memory")
#define WAITV0() asm volatile("s_waitcnt vmcnt(0)" ::: "memory")
#define SGB()    __builtin_amdgcn_sched_barrier(0)

// ---------------- fused weight cast fp32 -> bf16 ----------------
__global__ void __launch_bounds__(256)
cast3_kernel(const float* __restrict__ w0, const float* __restrict__ w1,
             const float* __restrict__ w2, u16* __restrict__ o0,
             u16* __restrict__ o1, u16* __restrict__ o2) {
  const int n04 = 2 * D_INNER * D_MODEL / 4;
  const int n14 = D_INNER * D_INNER / 4;
  const int n24 = D_MODEL * D_INNER / 4;
  int i = blockIdx.x * 256 + threadIdx.x;
  const float* src; u16* dst; int j;
  if (i < n04)            { src = w0; dst = o0; j = i; }
  else if (i < n04 + n14) { src = w1; dst = o1; j = i - n04; }
  else if (i < n04 + n14 + n24) { src = w2; dst = o2; j = i - n04 - n14; }
  else return;
  float4 v = ((const float4*)src)[j];
  u16x4 o;
  o.x = f2bf(v.x); o.y = f2bf(v.y); o.z = f2bf(v.z); o.w = f2bf(v.w);
  ((u16x4*)dst)[j] = o;
}

// ---------------- LayerNorm -> bf16 ----------------
__global__ void __launch_bounds__(256)
ln_kernel(const float* __restrict__ x, const float* __restrict__ w,
          const float* __restrict__ b, u16* __restrict__ xn) {
  const int row = blockIdx.x;
  const int t = threadIdx.x;
  const float4 v = ((const float4*)(x + (size_t)row * D_MODEL))[t];
  float s  = v.x + v.y + v.z + v.w;
  float ss = v.x * v.x + v.y * v.y + v.z * v.z + v.w * v.w;
#pragma unroll
  for (int o = 32; o > 0; o >>= 1) {
    s  += __shfl_xor(s, o);
    ss += __shfl_xor(ss, o);
  }
  __shared__ float red[8];
  const int wid = t >> 6, lane = t & 63;
  if (lane == 0) { red[wid] = s; red[4 + wid] = ss; }
  __syncthreads();
  s  = red[0] + red[1] + red[2] + red[3];
  ss = red[4] + red[5] + red[6] + red[7];
  const float mu  = s * (1.0f / D_MODEL);
  const float var = ss * (1.0f / D_MODEL) - mu * mu;
  const float rs  = rsqrtf(var + 1e-5f);
  const float4 wv = ((const float4*)w)[t];
  const float4 bv = ((const float4*)b)[t];
  u16x4 o4;
  o4.x = f2bf((v.x - mu) * rs * wv.x + bv.x);
  o4.y = f2bf((v.y - mu) * rs * wv.y + bv.y);
  o4.z = f2bf((v.z - mu) * rs * wv.z + bv.z);
  o4.w = f2bf((v.w - mu) * rs * wv.w + bv.w);
  ((u16x4*)(xn + (size_t)row * D_MODEL))[t] = o4;
}

// ======== 256x256 BK=64 8-wave PIPELINED GEMM (R10 structure, row-major) ====
// K-split support: blockIdx.y selects a K-half (Klen=K arg, stride=Kfull);
// EPI=1 writes bf16 partial at ob0 + y*M*N. Row-major XCD decode (R12's
// column-major decode regressed: FETCH 74->135MB).
#define MFMA_BF16 __builtin_amdgcn_mfma_f32_16x16x32_bf16

template<int EPI>
__global__ void __launch_bounds__(512, 2)
gemmP(const u16* __restrict__ A, const u16* __restrict__ Bm,
      int M, int N, int K, int Kfull,
      const float* __restrict__ ef, float* __restrict__ of,
      u16* __restrict__ ob0, u16* __restrict__ ob1) {
  constexpr int BN = 256, NF = 4, NF2 = 2, BBY = BN * 128, BH = BN / 128;
  __shared__ __align__(1024) char lds[65536 + 2 * BBY];
  const int tid = threadIdx.x, wid = tid >> 6, lane = tid & 63;
  const int nbx = N / BN;
  const int nwg = nbx * (M >> 8);
  const int bid = blockIdx.x;
  const int cpx = nwg >> 3;                       // nwg % 8 == 0 for our shapes
  const int swzb = (bid & 7) * cpx + (bid >> 3);  // XCD-aware swizzle
  const int bx = swzb % nbx, by = swzb / nbx;     // row-major decode (R10)
  const size_t m0 = (size_t)by << 8;
  const size_t n0 = (size_t)bx * BN;
  const int wr = wid >> 2, wc = wid & 3;
  const size_t rb = (size_t)Kfull * 2;
  const size_t kofs = (size_t)blockIdx.y * (size_t)K * 2;   // K-split byte offset

  const int strow = lane >> 3;
  const int stchk = (lane & 7) ^ strow;
  const char* gA = (const char*)A  + (m0 + (size_t)(wid * 8 + strow)) * rb + stchk * 16 + kofs;
  const char* gB = (const char*)Bm + (n0 + (size_t)(wid * 8 + strow)) * rb + stchk * 16 + kofs;
  const int sdw = wid * 1024;

  auto ST_A = [&](int t) {
    char* d = lds + (t & 1) * 32768 + sdw;
    const char* s = gA + (size_t)t * 128;
#pragma unroll
    for (int h = 0; h < 2; ++h) {
      gl_lds16(s + (size_t)(h * 128) * rb,      d + h * 16384);
      gl_lds16(s + (size_t)(h * 128 + 64) * rb, d + h * 16384 + 8192);
    }
  };
  auto ST_B = [&](int t) {
    char* d = lds + 65536 + (t & 1) * BBY + sdw;
    const char* s = gB + (size_t)t * 128;
#pragma unroll
    for (int h = 0; h < BH; ++h) {
      gl_lds16(s + (size_t)(h * 128) * rb,      d + h * 16384);
      gl_lds16(s + (size_t)(h * 128 + 64) * rb, d + h * 16384 + 8192);
    }
  };

  const int q = lane >> 4, r15 = lane & 15;
  const int kx0 = ((q ^ (r15 & 7)) << 4);
  const int kx1 = (((4 + q) ^ (r15 & 7)) << 4);
  const int arow = r15 * 128;
  const int bwoff = (wc >> 1) * 16384;
  const int brow  = ((wc & 1) * 64 + r15) * 128;

  bf16x8 af0[8], af1[8], b01[NF2], b23[NF2], c01[NF2], c23[NF2];
  f32x4 acc[8][NF] = {};

#define RDA(dst, kx, base) _Pragma("unroll") \
  for (int mf = 0; mf < 8; ++mf) dst[mf] = *(const bf16x8*)((base) + mf * 2048 + arow + (kx));
#define RDB(dst, kx, base, nf0) _Pragma("unroll") \
  for (int nf = 0; nf < NF2; ++nf) dst[nf] = *(const bf16x8*)((base) + (nf0 + nf) * 2048 + brow + (kx));
#define MM(afr, bfr, nf0) do { __builtin_amdgcn_s_setprio(1); _Pragma("unroll") \
  for (int mf = 0; mf < 8; ++mf) _Pragma("unroll") \
    for (int nf = 0; nf < NF2; ++nf) \
      acc[mf][nf0 + nf] = MFMA_BF16(afr[mf], bfr[nf], acc[mf][nf0 + nf], 0, 0, 0); \
  __builtin_amdgcn_s_setprio(0); } while (0)

  const int nk = K >> 6;

  ST_A(0); ST_B(0);
  WAITV0();
  SBAR();
  {
    const char* Ab = lds + wr * 16384;
    const char* Bb = lds + 65536 + bwoff;
    RDA(af0, kx0, Ab);
    RDB(b01, kx0, Bb, 0);
  }

  for (int t = 0; t < nk; ++t) {
    const int p = t & 1;
    const char* Ab = lds + p * 32768 + wr * 16384;
    const char* Bb = lds + 65536 + p * BBY + bwoff;
    const char* An = lds + (p ^ 1) * 32768 + wr * 16384;
    const char* Bn = lds + 65536 + (p ^ 1) * BBY + bwoff;
    const bool pf = (t + 1 < nk);

    if (pf) ST_A(t + 1);
    RDB(b23, kx0, Bb, NF2);
    SGB();
    MM(af0, b01, 0);
    SGB();

    if (pf) ST_B(t + 1);
    RDA(af1, kx1, Ab);
    RDB(c01, kx1, Bb, 0);
    SGB();
    MM(af0, b23, NF2);
    SGB();

    RDB(c23, kx1, Bb, NF2);
    SGB();
    MM(af1, c01, 0);
    SGB();

    MM(af1, c23, NF2);
    if (pf) {
      WAITV0();
      SBAR();
      RDA(af0, kx0, An);
      RDB(b01, kx0, Bn, 0);
    }
  }

#undef RDA
#undef RDB
#undef MM

  const int c0 = lane & 15;
  const int r0 = (lane >> 4) << 2;
  const bool isz = (EPI == 0) && (n0 >= (size_t)D_INNER);
  u16* ob0p = (EPI == 1) ? (ob0 + (size_t)blockIdx.y * (size_t)M * N) : ob0;
#pragma unroll
  for (int mf = 0; mf < 8; ++mf) {
#pragma unroll
    for (int nf = 0; nf < NF; ++nf) {
#pragma unroll
      for (int rg = 0; rg < 4; ++rg) {
        const size_t row = m0 + (size_t)(wr * 128 + mf * 16 + r0 + rg);
        const size_t col = n0 + (size_t)(wc * 64 + nf * 16 + c0);
        const float v = acc[mf][nf][rg];
        if (EPI == 0) {
          if (!isz) ob0[row * D_INNER + col] = f2bf(v);
          else      ob1[row * D_INNER + (col - D_INNER)] = f2bf(siluf_(v));
        } else if (EPI == 1) {
          ob0p[row * (size_t)N + col] = f2bf(v);
        } else {
          of[row * (size_t)N + col] = v + ef[row * (size_t)N + col];
        }
      }
    }
  }
}

// ---- GEMM3 reduce: out = p0 + p1 + residual (vectorized) ----
__global__ void __launch_bounds__(256)
reduce3_kernel(const u16* __restrict__ part, const float* __restrict__ x,
               float* __restrict__ out) {
  const size_t MN = (size_t)M_ROWS * D_MODEL;
  const size_t i = ((size_t)blockIdx.x * 256 + threadIdx.x) * 4;
  const u16x4 a = *(const u16x4*)(part + i);
  const u16x4 b = *(const u16x4*)(part + MN + i);
  const float4 xv = *(const float4*)(x + i);
  float4 o;
  o.x = bf2f(a.x) + bf2f(b.x) + xv.x;
  o.y = bf2f(a.y) + bf2f(b.y) + xv.y;
  o.z = bf2f(a.z) + bf2f(b.z) + xv.z;
  o.w = bf2f(a.w) + bf2f(b.w) + xv.w;
  *(float4*)(out + i) = o;
}

// ---------------- causal depthwise conv (K=4) + SiLU, 4 ch/thread ----------------
__global__ void __launch_bounds__(256)
conv_silu_kernel(const u16* __restrict__ xin, const float* __restrict__ cw,
                 const float* __restrict__ cb, u16* __restrict__ xc) {
  const int c   = (blockIdx.x * 256 + threadIdx.x) * 4;
  const int l0  = blockIdx.y * 8;
  const int bat = blockIdx.z;
  const size_t base = ((size_t)bat * LSEQ) * D_INNER + c;
  float4 w[4];
#pragma unroll
  for (int j = 0; j < 4; ++j) w[j] = ((const float4*)cw)[c + j];
  const float4 bb = *(const float4*)(cb + c);
  float v[11][4];
#pragma unroll
  for (int i = 0; i < 11; ++i) {
    const int l = l0 - 3 + i;
    if (l >= 0) {
      const u16x4 u = *(const u16x4*)(xin + base + (size_t)l * D_INNER);
      v[i][0] = bf2f(u.x); v[i][1] = bf2f(u.y); v[i][2] = bf2f(u.z); v[i][3] = bf2f(u.w);
    } else {
      v[i][0] = v[i][1] = v[i][2] = v[i][3] = 0.0f;
    }
  }
  const float bba[4] = {bb.x, bb.y, bb.z, bb.w};
#pragma unroll
  for (int r = 0; r < 8; ++r) {
    u16x4 o;
#pragma unroll
    for (int j = 0; j < 4; ++j) {
      const float acc = bba[j] + w[j].x * v[r][j] + w[j].y * v[r + 1][j]
                      + w[j].z * v[r + 2][j] + w[j].w * v[r + 3][j];
      const float sv = siluf_(acc);
      if (j == 0) o.x = f2bf(sv);
      else if (j == 1) o.y = f2bf(sv);
      else if (j == 2) o.z = f2bf(sv);
      else o.w = f2bf(sv);
    }
    *(u16x4*)(xc + base + (size_t)(l0 + r) * D_INNER) = o;
  }
}

// ---------------- chunked scan: pass A (4 channels/thread) ----------------
__global__ void __launch_bounds__(256)
scan_a_kernel(const u16* __restrict__ g, const u16* __restrict__ xc,
              const float* __restrict__ gbias,
              float* __restrict__ cA, float* __restrict__ cB) {
  const int c   = (blockIdx.x * 256 + threadIdx.x) * 4;
  const int ch  = blockIdx.y;
  const int bat = blockIdx.z;
  const float4 bb = *(const float4*)(gbias + c);
  const float bba[4] = {bb.x, bb.y, bb.z, bb.w};
  size_t idx = ((size_t)bat * LSEQ + (size_t)ch * CHUNK) * D_INNER + c;
  float pA[4] = {1.0f, 1.0f, 1.0f, 1.0f};
  float hB[4] = {0.0f, 0.0f, 0.0f, 0.0f};
  for (int t = 0; t < CHUNK; ++t) {
    const u16x4 gg = *(const u16x4*)(g + idx);
    const u16x4 xx = *(const u16x4*)(xc + idx);
    const float gv[4] = {bf2f(gg.x), bf2f(gg.y), bf2f(gg.z), bf2f(gg.w)};
    const float xv[4] = {bf2f(xx.x), bf2f(xx.y), bf2f(xx.z), bf2f(xx.w)};
#pragma unroll
    for (int j = 0; j < 4; ++j) {
      const float a = sigmoidf_(gv[j] + bba[j]);
      pA[j] *= a;
      hB[j] = a * hB[j] + (1.0f - a) * xv[j];
    }
    idx += D_INNER;
  }
  const size_t o = ((size_t)bat * NCHUNK + ch) * D_INNER + c;
  *(float4*)(cA + o) = make_float4(pA[0], pA[1], pA[2], pA[3]);
  *(float4*)(cB + o) = make_float4(hB[0], hB[1], hB[2], hB[3]);
}

// ---------------- pass B: serial scan over chunk summaries ----------------
__global__ void __launch_bounds__(256)
scan_b_kernel(const float* __restrict__ cA, const float* __restrict__ cB,
              float* __restrict__ carry) {
  const int tid = blockIdx.x * 256 + threadIdx.x;
  const int bat = tid >> 11;
  const int c   = tid & (D_INNER - 1);
  float h = 0.0f;
  const size_t base = (size_t)bat * NCHUNK * D_INNER + c;
  for (int i = 0; i < NCHUNK; ++i) {
    const size_t o = base + (size_t)i * D_INNER;
    carry[o] = h;
    h = cA[o] * h + cB[o];
  }
}

// ---------------- pass C: apply carry, gate by silu(z), 4 ch/thread ----------------
__global__ void __launch_bounds__(256)
scan_c_kernel(const u16* __restrict__ g, const u16* __restrict__ xc,
              const u16* __restrict__ sz, const float* __restrict__ gbias,
              const float* __restrict__ carry, u16* __restrict__ yg) {
  const int c   = (blockIdx.x * 256 + threadIdx.x) * 4;
  const int ch  = blockIdx.y;
  const int bat = blockIdx.z;
  const float4 bb = *(const float4*)(gbias + c);
  const float bba[4] = {bb.x, bb.y, bb.z, bb.w};
  const float4 h4 = *(const float4*)(carry + ((size_t)bat * NCHUNK + ch) * D_INNER + c);
  float h[4] = {h4.x, h4.y, h4.z, h4.w};
  size_t idx = ((size_t)bat * LSEQ + (size_t)ch * CHUNK) * D_INNER + c;
  for (int t = 0; t < CHUNK; ++t) {
    const u16x4 gg = *(const u16x4*)(g + idx);
    const u16x4 xx = *(const u16x4*)(xc + idx);
    const u16x4 zz = *(const u16x4*)(sz + idx);
    const float gv[4] = {bf2f(gg.x), bf2f(gg.y), bf2f(gg.z), bf2f(gg.w)};
    const float xv[4] = {bf2f(xx.x), bf2f(xx.y), bf2f(xx.z), bf2f(xx.w)};
    const float zv[4] = {bf2f(zz.x), bf2f(zz.y), bf2f(zz.z), bf2f(zz.w)};
    u16x4 o;
#pragma unroll
    for (int j = 0; j < 4; ++j) {
      const float a = sigmoidf_(gv[j] + bba[j]);
      h[j] = a * h[j] + (1.0f - a) * xv[j];
      const u16 ob = f2bf(h[j] * zv[j]);
      if (j == 0) o.x = ob; else if (j == 1) o.y = ob;
      else if (j == 2) o.z = ob; else o.w = ob;
    }
    *(u16x4*)(yg + idx) = o;
    idx += D_INNER;
  }
}

extern "C" void kernel_launch(void* const* d_in, const int* in_sizes, int n_in,
                              void* d_out, int out_size, void* d_ws, size_t ws_size,
                              hipStream_t stream) {
  const float* x         = (const float*)d_in[0];
  const float* norm_w    = (const float*)d_in[1];
  const float* norm_b    = (const float*)d_in[2];
  const float* in_proj_w = (const float*)d_in[3];
  const float* conv_w    = (const float*)d_in[4];
  const float* conv_b    = (const float*)d_in[5];
  const float* gate_w    = (const float*)d_in[6];
  const float* gate_b    = (const float*)d_in[7];
  const float* out_proj_w= (const float*)d_in[8];
  float* out = (float*)d_out;

  char* p = (char*)d_ws;
  u16* xn      = (u16*)p; p += (size_t)M_ROWS * D_MODEL * 2;
  u16* w_in    = (u16*)p; p += (size_t)2 * D_INNER * D_MODEL * 2;
  u16* w_gate  = (u16*)p; p += (size_t)D_INNER * D_INNER * 2;
  u16* w_out   = (u16*)p; p += (size_t)D_MODEL * D_INNER * 2;
  u16* x_inner = (u16*)p; p += (size_t)M_ROWS * D_INNER * 2;
  u16* szb     = (u16*)p; p += (size_t)M_ROWS * D_INNER * 2;
  u16* xconv   = (u16*)p; p += (size_t)M_ROWS * D_INNER * 2;
  u16* gbuf    = (u16*)p; p += (size_t)M_ROWS * D_INNER * 2;
  u16* yg      = (u16*)p; p += (size_t)M_ROWS * D_INNER * 2;
  u16* part    = (u16*)p; p += (size_t)2 * M_ROWS * D_MODEL * 2;   // GEMM3 K-split partials
  float* cA    = (float*)p; p += (size_t)BATCH * NCHUNK * D_INNER * 4;
  float* cB    = (float*)p; p += (size_t)BATCH * NCHUNK * D_INNER * 4;
  float* carry = (float*)p; p += (size_t)BATCH * NCHUNK * D_INNER * 4;
  if ((size_t)(p - (char*)d_ws) > ws_size) return;

  const int ncast4 = (2 * D_INNER * D_MODEL + D_INNER * D_INNER + D_MODEL * D_INNER) / 4;
  cast3_kernel<<<dim3((ncast4 + 255) / 256), 256, 0, stream>>>(
      in_proj_w, gate_w, out_proj_w, w_in, w_gate, w_out);

  ln_kernel<<<dim3(M_ROWS), 256, 0, stream>>>(x, norm_w, norm_b, xn);

  gemmP<0><<<dim3((M_ROWS / 256) * (2 * D_INNER / 256)), 512, 0, stream>>>(
      xn, w_in, M_ROWS, 2 * D_INNER, D_MODEL, D_MODEL, nullptr, nullptr, x_inner, szb);

  conv_silu_kernel<<<dim3(D_INNER / 1024, LSEQ / 8, BATCH), 256, 0, stream>>>(
      x_inner, conv_w, conv_b, xconv);

  gemmP<1><<<dim3((M_ROWS / 256) * (D_INNER / 256)), 512, 0, stream>>>(
      xconv, w_gate, M_ROWS, D_INNER, D_INNER, D_INNER, nullptr, nullptr, gbuf, nullptr);

  scan_a_kernel<<<dim3(D_INNER / 1024, NCHUNK, BATCH), 256, 0, stream>>>(gbuf, xconv, gate_b, cA, cB);
  scan_b_kernel<<<dim3(BATCH * D_INNER / 256), 256, 0, stream>>>(cA, cB, carry);
  scan_c_kernel<<<dim3(D_INNER / 1024, NCHUNK, BATCH), 256, 0, stream>>>(gbuf, xconv, szb, gate_b, carry, yg);

  // GEMM3: K split in 2 (blockIdx.y), 256 co-resident blocks; bf16 partials
  gemmP<1><<<dim3((M_ROWS / 256) * (D_MODEL / 256), 2), 512, 0, stream>>>(
      yg, w_out, M_ROWS, D_MODEL, D_INNER / 2, D_INNER, nullptr, nullptr, part, nullptr);

  reduce3_kernel<<<dim3(M_ROWS * D_MODEL / 4 / 256), 256, 0, stream>>>(part, x, out);
}

// Round 14
// 303.186 us; speedup vs baseline: 1.2566x; 1.2566x over previous
//
#include <hip/hip_runtime.h>
#include <cstdint>

#define D_MODEL 1024
#define D_INNER 2048
#define LSEQ    4096
#define BATCH   2
#define M_ROWS  (BATCH * LSEQ)   // 8192
#define CHUNK   64
#define NCHUNK  (LSEQ / CHUNK)   // 64

typedef unsigned short u16;
typedef __bf16 bf16x8 __attribute__((ext_vector_type(8)));
typedef float f32x4 __attribute__((ext_vector_type(4)));
typedef u16 u16x4 __attribute__((ext_vector_type(4)));

__device__ __forceinline__ u16 f2bf(float f) {
  union { float f; unsigned u; } x; x.f = f;
  unsigned u = x.u;
  unsigned r = (u + 0x7FFFu + ((u >> 16) & 1u)) >> 16;
  return (u16)r;
}
__device__ __forceinline__ float bf2f(u16 h) {
  union { unsigned u; float f; } x; x.u = ((unsigned)h) << 16;
  return x.f;
}
__device__ __forceinline__ float sigmoidf_(float v) { return 1.0f / (1.0f + expf(-v)); }
__device__ __forceinline__ float siluf_(float v)    { return v / (1.0f + expf(-v)); }

__device__ __forceinline__ void gl_lds16(const void* g, void* l) {
  __builtin_amdgcn_global_load_lds(
      (const __attribute__((address_space(1))) void*)g,
      (__attribute__((address_space(3))) void*)l, 16, 0, 0);
}

#define SBAR()   asm volatile("s_barrier" ::: "memory")
#define WAITV0() asm volatile("s_waitcnt vmcnt(0)" ::: "memory")
#define SGB()    __builtin_amdgcn_sched_barrier(0)

// ---------------- fused weight cast fp32 -> bf16 ----------------
__global__ void __launch_bounds__(256)
cast3_kernel(const float* __restrict__ w0, const float* __restrict__ w1,
             const float* __restrict__ w2, u16* __restrict__ o0,
             u16* __restrict__ o1, u16* __restrict__ o2) {
  const int n04 = 2 * D_INNER * D_MODEL / 4;
  const int n14 = D_INNER * D_INNER / 4;
  const int n24 = D_MODEL * D_INNER / 4;
  int i = blockIdx.x * 256 + threadIdx.x;
  const float* src; u16* dst; int j;
  if (i < n04)            { src = w0; dst = o0; j = i; }
  else if (i < n04 + n14) { src = w1; dst = o1; j = i - n04; }
  else if (i < n04 + n14 + n24) { src = w2; dst = o2; j = i - n04 - n14; }
  else return;
  float4 v = ((const float4*)src)[j];
  u16x4 o;
  o.x = f2bf(v.x); o.y = f2bf(v.y); o.z = f2bf(v.z); o.w = f2bf(v.w);
  ((u16x4*)dst)[j] = o;
}

// ---------------- LayerNorm -> bf16 ----------------
__global__ void __launch_bounds__(256)
ln_kernel(const float* __restrict__ x, const float* __restrict__ w,
          const float* __restrict__ b, u16* __restrict__ xn) {
  const int row = blockIdx.x;
  const int t = threadIdx.x;
  const float4 v = ((const float4*)(x + (size_t)row * D_MODEL))[t];
  float s  = v.x + v.y + v.z + v.w;
  float ss = v.x * v.x + v.y * v.y + v.z * v.z + v.w * v.w;
#pragma unroll
  for (int o = 32; o > 0; o >>= 1) {
    s  += __shfl_xor(s, o);
    ss += __shfl_xor(ss, o);
  }
  __shared__ float red[8];
  const int wid = t >> 6, lane = t & 63;
  if (lane == 0) { red[wid] = s; red[4 + wid] = ss; }
  __syncthreads();
  s  = red[0] + red[1] + red[2] + red[3];
  ss = red[4] + red[5] + red[6] + red[7];
  const float mu  = s * (1.0f / D_MODEL);
  const float var = ss * (1.0f / D_MODEL) - mu * mu;
  const float rs  = rsqrtf(var + 1e-5f);
  const float4 wv = ((const float4*)w)[t];
  const float4 bv = ((const float4*)b)[t];
  u16x4 o4;
  o4.x = f2bf((v.x - mu) * rs * wv.x + bv.x);
  o4.y = f2bf((v.y - mu) * rs * wv.y + bv.y);
  o4.z = f2bf((v.z - mu) * rs * wv.z + bv.z);
  o4.w = f2bf((v.w - mu) * rs * wv.w + bv.w);
  ((u16x4*)(xn + (size_t)row * D_MODEL))[t] = o4;
}

// ======== 256x256 BK=64 8-wave PIPELINED GEMM (R10 structure, row-major) ====
// K-split: blockIdx.y selects a K-slice (Klen=K arg, row stride=Kfull);
// EPI=1 writes bf16 output at ob0 + y*M*N.
#define MFMA_BF16 __builtin_amdgcn_mfma_f32_16x16x32_bf16

template<int EPI>
__global__ void __launch_bounds__(512, 2)
gemmP(const u16* __restrict__ A, const u16* __restrict__ Bm,
      int M, int N, int K, int Kfull,
      const float* __restrict__ ef, float* __restrict__ of,
      u16* __restrict__ ob0, u16* __restrict__ ob1) {
  constexpr int BN = 256, NF = 4, NF2 = 2, BBY = BN * 128, BH = BN / 128;
  __shared__ __align__(1024) char lds[65536 + 2 * BBY];
  const int tid = threadIdx.x, wid = tid >> 6, lane = tid & 63;
  const int nbx = N / BN;
  const int nwg = nbx * (M >> 8);
  const int bid = blockIdx.x;
  const int cpx = nwg >> 3;                       // nwg % 8 == 0 for our shapes
  const int swzb = (bid & 7) * cpx + (bid >> 3);  // XCD-aware swizzle
  const int bx = swzb % nbx, by = swzb / nbx;     // row-major decode (R10)
  const size_t m0 = (size_t)by << 8;
  const size_t n0 = (size_t)bx * BN;
  const int wr = wid >> 2, wc = wid & 3;
  const size_t rb = (size_t)Kfull * 2;
  const size_t kofs = (size_t)blockIdx.y * (size_t)K * 2;

  const int strow = lane >> 3;
  const int stchk = (lane & 7) ^ strow;
  const char* gA = (const char*)A  + (m0 + (size_t)(wid * 8 + strow)) * rb + stchk * 16 + kofs;
  const char* gB = (const char*)Bm + (n0 + (size_t)(wid * 8 + strow)) * rb + stchk * 16 + kofs;
  const int sdw = wid * 1024;

  auto ST_A = [&](int t) {
    char* d = lds + (t & 1) * 32768 + sdw;
    const char* s = gA + (size_t)t * 128;
#pragma unroll
    for (int h = 0; h < 2; ++h) {
      gl_lds16(s + (size_t)(h * 128) * rb,      d + h * 16384);
      gl_lds16(s + (size_t)(h * 128 + 64) * rb, d + h * 16384 + 8192);
    }
  };
  auto ST_B = [&](int t) {
    char* d = lds + 65536 + (t & 1) * BBY + sdw;
    const char* s = gB + (size_t)t * 128;
#pragma unroll
    for (int h = 0; h < BH; ++h) {
      gl_lds16(s + (size_t)(h * 128) * rb,      d + h * 16384);
      gl_lds16(s + (size_t)(h * 128 + 64) * rb, d + h * 16384 + 8192);
    }
  };

  const int q = lane >> 4, r15 = lane & 15;
  const int kx0 = ((q ^ (r15 & 7)) << 4);
  const int kx1 = (((4 + q) ^ (r15 & 7)) << 4);
  const int arow = r15 * 128;
  const int bwoff = (wc >> 1) * 16384;
  const int brow  = ((wc & 1) * 64 + r15) * 128;

  bf16x8 af0[8], af1[8], b01[NF2], b23[NF2], c01[NF2], c23[NF2];
  f32x4 acc[8][NF] = {};

#define RDA(dst, kx, base) _Pragma("unroll") \
  for (int mf = 0; mf < 8; ++mf) dst[mf] = *(const bf16x8*)((base) + mf * 2048 + arow + (kx));
#define RDB(dst, kx, base, nf0) _Pragma("unroll") \
  for (int nf = 0; nf < NF2; ++nf) dst[nf] = *(const bf16x8*)((base) + (nf0 + nf) * 2048 + brow + (kx));
#define MM(afr, bfr, nf0) do { __builtin_amdgcn_s_setprio(1); _Pragma("unroll") \
  for (int mf = 0; mf < 8; ++mf) _Pragma("unroll") \
    for (int nf = 0; nf < NF2; ++nf) \
      acc[mf][nf0 + nf] = MFMA_BF16(afr[mf], bfr[nf], acc[mf][nf0 + nf], 0, 0, 0); \
  __builtin_amdgcn_s_setprio(0); } while (0)

  const int nk = K >> 6;

  ST_A(0); ST_B(0);
  WAITV0();
  SBAR();
  {
    const char* Ab = lds + wr * 16384;
    const char* Bb = lds + 65536 + bwoff;
    RDA(af0, kx0, Ab);
    RDB(b01, kx0, Bb, 0);
  }

  for (int t = 0; t < nk; ++t) {
    const int p = t & 1;
    const char* Ab = lds + p * 32768 + wr * 16384;
    const char* Bb = lds + 65536 + p * BBY + bwoff;
    const char* An = lds + (p ^ 1) * 32768 + wr * 16384;
    const char* Bn = lds + 65536 + (p ^ 1) * BBY + bwoff;
    const bool pf = (t + 1 < nk);

    if (pf) ST_A(t + 1);
    RDB(b23, kx0, Bb, NF2);
    SGB();
    MM(af0, b01, 0);
    SGB();

    if (pf) ST_B(t + 1);
    RDA(af1, kx1, Ab);
    RDB(c01, kx1, Bb, 0);
    SGB();
    MM(af0, b23, NF2);
    SGB();

    RDB(c23, kx1, Bb, NF2);
    SGB();
    MM(af1, c01, 0);
    SGB();

    MM(af1, c23, NF2);
    if (pf) {
      WAITV0();
      SBAR();
      RDA(af0, kx0, An);
      RDB(b01, kx0, Bn, 0);
    }
  }

#undef RDA
#undef RDB
#undef MM

  const int c0 = lane & 15;
  const int r0 = (lane >> 4) << 2;
  const bool isz = (EPI == 0) && (n0 >= (size_t)D_INNER);
  u16* ob0p = (EPI == 1) ? (ob0 + (size_t)blockIdx.y * (size_t)M * N) : ob0;
#pragma unroll
  for (int mf = 0; mf < 8; ++mf) {
#pragma unroll
    for (int nf = 0; nf < NF; ++nf) {
#pragma unroll
      for (int rg = 0; rg < 4; ++rg) {
        const size_t row = m0 + (size_t)(wr * 128 + mf * 16 + r0 + rg);
        const size_t col = n0 + (size_t)(wc * 64 + nf * 16 + c0);
        const float v = acc[mf][nf][rg];
        if (EPI == 0) {
          if (!isz) ob0[row * D_INNER + col] = f2bf(v);
          else      ob1[row * D_INNER + (col - D_INNER)] = f2bf(siluf_(v));
        } else if (EPI == 1) {
          ob0p[row * (size_t)N + col] = f2bf(v);
        } else {
          of[row * (size_t)N + col] = v + ef[row * (size_t)N + col];
        }
      }
    }
  }
}

// ---- GEMM3 reduce: out = p0 + p1 + residual (vectorized) ----
__global__ void __launch_bounds__(256)
reduce3_kernel(const u16* __restrict__ part, const float* __restrict__ x,
               float* __restrict__ out) {
  const size_t MN = (size_t)M_ROWS * D_MODEL;
  const size_t i = ((size_t)blockIdx.x * 256 + threadIdx.x) * 4;
  const u16x4 a = *(const u16x4*)(part + i);
  const u16x4 b = *(const u16x4*)(part + MN + i);
  const float4 xv = *(const float4*)(x + i);
  float4 o;
  o.x = bf2f(a.x) + bf2f(b.x) + xv.x;
  o.y = bf2f(a.y) + bf2f(b.y) + xv.y;
  o.z = bf2f(a.z) + bf2f(b.z) + xv.z;
  o.w = bf2f(a.w) + bf2f(b.w) + xv.w;
  *(float4*)(out + i) = o;
}

// ---------------- causal depthwise conv (K=4) + SiLU (R10 1ch) ----------------
__global__ void __launch_bounds__(256)
conv_silu_kernel(const u16* __restrict__ xin, const float* __restrict__ cw,
                 const float* __restrict__ cb, u16* __restrict__ xc) {
  const int c   = blockIdx.x * 256 + threadIdx.x;
  const int l0  = blockIdx.y * 8;
  const int bat = blockIdx.z;
  const size_t base = ((size_t)bat * LSEQ) * D_INNER + c;
  const float w0 = cw[c * 4 + 0], w1 = cw[c * 4 + 1], w2 = cw[c * 4 + 2], w3 = cw[c * 4 + 3];
  const float bb = cb[c];
  float v[11];
#pragma unroll
  for (int i = 0; i < 11; ++i) {
    const int l = l0 - 3 + i;
    v[i] = (l >= 0) ? bf2f(xin[base + (size_t)l * D_INNER]) : 0.0f;
  }
#pragma unroll
  for (int r = 0; r < 8; ++r) {
    const float acc = bb + w0 * v[r] + w1 * v[r + 1] + w2 * v[r + 2] + w3 * v[r + 3];
    xc[base + (size_t)(l0 + r) * D_INNER] = f2bf(siluf_(acc));
  }
}

// ---------------- chunked scan: pass A (2 ch/thread, CHUNK=64) ----------------
__global__ void __launch_bounds__(256)
scan_a_kernel(const u16* __restrict__ g, const u16* __restrict__ xc,
              const float* __restrict__ gbias,
              float* __restrict__ cA, float* __restrict__ cB) {
  const int c   = (blockIdx.x * 256 + threadIdx.x) * 2;
  const int ch  = blockIdx.y;
  const int bat = blockIdx.z;
  const float bb0 = gbias[c], bb1 = gbias[c + 1];
  size_t idx = ((size_t)bat * LSEQ + (size_t)ch * CHUNK) * D_INNER + c;
  float pA0 = 1.0f, hB0 = 0.0f, pA1 = 1.0f, hB1 = 0.0f;
  for (int t = 0; t < CHUNK; ++t) {
    const ushort2 gg = *(const ushort2*)(g + idx);
    const ushort2 xx = *(const ushort2*)(xc + idx);
    const float a0 = sigmoidf_(bf2f(gg.x) + bb0);
    const float a1 = sigmoidf_(bf2f(gg.y) + bb1);
    pA0 *= a0; hB0 = a0 * hB0 + (1.0f - a0) * bf2f(xx.x);
    pA1 *= a1; hB1 = a1 * hB1 + (1.0f - a1) * bf2f(xx.y);
    idx += D_INNER;
  }
  const size_t o = ((size_t)bat * NCHUNK + ch) * D_INNER + c;
  *(float2*)(cA + o) = make_float2(pA0, pA1);
  *(float2*)(cB + o) = make_float2(hB0, hB1);
}

// ---------------- pass B: serial scan over chunk summaries ----------------
__global__ void __launch_bounds__(256)
scan_b_kernel(const float* __restrict__ cA, const float* __restrict__ cB,
              float* __restrict__ carry) {
  const int tid = blockIdx.x * 256 + threadIdx.x;
  const int bat = tid >> 11;
  const int c   = tid & (D_INNER - 1);
  float h = 0.0f;
  const size_t base = (size_t)bat * NCHUNK * D_INNER + c;
  for (int i = 0; i < NCHUNK; ++i) {
    const size_t o = base + (size_t)i * D_INNER;
    carry[o] = h;
    h = cA[o] * h + cB[o];
  }
}

// ---------------- pass C: apply carry, gate by silu(z) (2 ch/thread) ----------------
__global__ void __launch_bounds__(256)
scan_c_kernel(const u16* __restrict__ g, const u16* __restrict__ xc,
              const u16* __restrict__ sz, const float* __restrict__ gbias,
              const float* __restrict__ carry, u16* __restrict__ yg) {
  const int c   = (blockIdx.x * 256 + threadIdx.x) * 2;
  const int ch  = blockIdx.y;
  const int bat = blockIdx.z;
  const float bb0 = gbias[c], bb1 = gbias[c + 1];
  const float2 h2 = *(const float2*)(carry + ((size_t)bat * NCHUNK + ch) * D_INNER + c);
  float h0 = h2.x, h1 = h2.y;
  size_t idx = ((size_t)bat * LSEQ + (size_t)ch * CHUNK) * D_INNER + c;
  for (int t = 0; t < CHUNK; ++t) {
    const ushort2 gg = *(const ushort2*)(g + idx);
    const ushort2 xx = *(const ushort2*)(xc + idx);
    const ushort2 zz = *(const ushort2*)(sz + idx);
    const float a0 = sigmoidf_(bf2f(gg.x) + bb0);
    const float a1 = sigmoidf_(bf2f(gg.y) + bb1);
    h0 = a0 * h0 + (1.0f - a0) * bf2f(xx.x);
    h1 = a1 * h1 + (1.0f - a1) * bf2f(xx.y);
    ushort2 o2;
    o2.x = f2bf(h0 * bf2f(zz.x));
    o2.y = f2bf(h1 * bf2f(zz.y));
    *(ushort2*)(yg + idx) = o2;
    idx += D_INNER;
  }
}

extern "C" void kernel_launch(void* const* d_in, const int* in_sizes, int n_in,
                              void* d_out, int out_size, void* d_ws, size_t ws_size,
                              hipStream_t stream) {
  const float* x         = (const float*)d_in[0];
  const float* norm_w    = (const float*)d_in[1];
  const float* norm_b    = (const float*)d_in[2];
  const float* in_proj_w = (const float*)d_in[3];
  const float* conv_w    = (const float*)d_in[4];
  const float* conv_b    = (const float*)d_in[5];
  const float* gate_w    = (const float*)d_in[6];
  const float* gate_b    = (const float*)d_in[7];
  const float* out_proj_w= (const float*)d_in[8];
  float* out = (float*)d_out;

  char* p = (char*)d_ws;
  u16* xn      = (u16*)p; p += (size_t)M_ROWS * D_MODEL * 2;
  u16* w_in    = (u16*)p; p += (size_t)2 * D_INNER * D_MODEL * 2;
  u16* w_gate  = (u16*)p; p += (size_t)D_INNER * D_INNER * 2;
  u16* w_out   = (u16*)p; p += (size_t)D_MODEL * D_INNER * 2;
  u16* x_inner = (u16*)p; p += (size_t)M_ROWS * D_INNER * 2;
  u16* szb     = (u16*)p; p += (size_t)M_ROWS * D_INNER * 2;
  u16* xconv   = (u16*)p; p += (size_t)M_ROWS * D_INNER * 2;
  u16* gbuf    = (u16*)p; p += (size_t)M_ROWS * D_INNER * 2;
  u16* yg      = (u16*)p; p += (size_t)M_ROWS * D_INNER * 2;
  u16* part    = (u16*)p; p += (size_t)2 * M_ROWS * D_MODEL * 2;   // GEMM3 K-split partials
  float* cA    = (float*)p; p += (size_t)BATCH * NCHUNK * D_INNER * 4;
  float* cB    = (float*)p; p += (size_t)BATCH * NCHUNK * D_INNER * 4;
  float* carry = (float*)p; p += (size_t)BATCH * NCHUNK * D_INNER * 4;
  if ((size_t)(p - (char*)d_ws) > ws_size) return;

  const int ncast4 = (2 * D_INNER * D_MODEL + D_INNER * D_INNER + D_MODEL * D_INNER) / 4;
  cast3_kernel<<<dim3((ncast4 + 255) / 256), 256, 0, stream>>>(
      in_proj_w, gate_w, out_proj_w, w_in, w_gate, w_out);

  ln_kernel<<<dim3(M_ROWS), 256, 0, stream>>>(x, norm_w, norm_b, xn);

  gemmP<0><<<dim3((M_ROWS / 256) * (2 * D_INNER / 256)), 512, 0, stream>>>(
      xn, w_in, M_ROWS, 2 * D_INNER, D_MODEL, D_MODEL, nullptr, nullptr, x_inner, szb);

  conv_silu_kernel<<<dim3(D_INNER / 256, LSEQ / 8, BATCH), 256, 0, stream>>>(
      x_inner, conv_w, conv_b, xconv);

  gemmP<1><<<dim3((M_ROWS / 256) * (D_INNER / 256)), 512, 0, stream>>>(
      xconv, w_gate, M_ROWS, D_INNER, D_INNER, D_INNER, nullptr, nullptr, gbuf, nullptr);

  scan_a_kernel<<<dim3(D_INNER / 512, NCHUNK, BATCH), 256, 0, stream>>>(gbuf, xconv, gate_b, cA, cB);
  scan_b_kernel<<<dim3(BATCH * D_INNER / 256), 256, 0, stream>>>(cA, cB, carry);
  scan_c_kernel<<<dim3(D_INNER / 512, NCHUNK, BATCH), 256, 0, stream>>>(gbuf, xconv, szb, gate_b, carry, yg);

  // GEMM3: K split in 2 (blockIdx.y), 16 tile-slots/CU instead of 32
  gemmP<1><<<dim3((M_ROWS / 256) * (D_MODEL / 256), 2), 512, 0, stream>>>(
      yg, w_out, M_ROWS, D_MODEL, D_INNER / 2, D_INNER, nullptr, nullptr, part, nullptr);

  reduce3_kernel<<<dim3(M_ROWS * D_MODEL / 4 / 256), 256, 0, stream>>>(part, x, out);
}